// Round 3
// baseline (281.571 us; speedup 1.0000x reference)
//
#include <hip/hip_runtime.h>

// OctVolSynth: element-wise over 256^3 volume.
//   scaling = lut[label]; v = scaling*texture; v = (v==0) ? 1 : v;
//   out0 = parenchyma * v;  out1 = (label != 0) ? 1.0f : 0.0f
//
// R1-R7 all land at 98-99us regardless of structure. R7 (asm-forced 6-deep
// MLP, 8 waves/SIMD) proved it is NOT latency-bound: ~32MB in flight
// device-wide, duration unchanged => throughput-limited at 3.24 TB/s combined
// while HBM sits at 30%. Counter evidence: FETCH_SIZE=98MB steady-state vs
// 192MB of inputs and 256MB L3 -- the 128MB of streaming output writes evict
// half the input set from Infinity Cache every iteration (320MB working set >
// 256MB L3). R8, single variable vs R7: stores become non-temporal (`nt`,
// write-around) so outputs stop allocating in L3 and the 192MB input set
// stays fully resident. Predict FETCH 98MB -> <30MB; dur 98.7 -> 60-75us if
// the re-fetch/thrash was the limiter.

#define N_ELEMS (256 * 256 * 256)
#define LUT_SIZE 302
#define BLOCK 512
#define CHUNKS 2   // float4 chunks per thread per stream -> 8 elems/thread

typedef float vfloat4 __attribute__((ext_vector_type(4)));
typedef int   vint4   __attribute__((ext_vector_type(4)));

// Loads: volatile, mutual program order pinned, results untracked by the
// compiler's waitcnt logic (manual s_waitcnt below). SADDR form: 32-bit
// voffset + SGPR-pair base, 13-bit imm offset.
#define GLOAD(dst, off, base, imm)                                    \
  asm volatile("global_load_dwordx4 %0, %1, %2 offset:" #imm          \
               : "=&v"(dst) : "v"(off), "s"(base))

// Stores: non-temporal (nt) -> write-around, do not allocate in L2/MALL.
#define GSTORE_NT(src, off, base, imm)                                \
  asm volatile("global_store_dwordx4 %0, %1, %2 offset:" #imm " nt"   \
               :: "v"(off), "v"(src), "s"(base) : "memory")

#define WAITCNT_VM(n)                                                 \
  do {                                                                \
    asm volatile("s_waitcnt vmcnt(" #n ")" ::: "memory");             \
    __builtin_amdgcn_sched_barrier(0);                                \
  } while (0)

__global__ __launch_bounds__(BLOCK) void octvolsynth_r8(
    const int* __restrict__ labels,
    const float* __restrict__ parenchyma,
    const float* __restrict__ texture,
    const float* __restrict__ lut,
    float* __restrict__ out)
{
    __shared__ float s_lut[LUT_SIZE];
    for (int i = threadIdx.x; i < LUT_SIZE; i += BLOCK) s_lut[i] = lut[i];
    __syncthreads();   // drains vmcnt -> manual counting starts at 0

    const unsigned wid  = threadIdx.x >> 6;
    const unsigned lane = threadIdx.x & 63;
    // byte offset; each wave owns CHUNKS KB contiguous per stream
    const unsigned off = blockIdx.x * (BLOCK * CHUNKS * 16u)
                       + wid * (CHUNKS * 64u * 16u)
                       + lane * 16u;

    const float* outm = out + N_ELEMS;   // mask plane base

    // ---- issue phase: 6 independent loads, order = (l,p,x) per chunk ----
    vint4   l0, l1;
    vfloat4 p0, p1, x0, x1;
    GLOAD(l0, off, labels,     0);
    GLOAD(p0, off, parenchyma, 0);
    GLOAD(x0, off, texture,    0);
    GLOAD(l1, off, labels,     1024);
    GLOAD(p1, off, parenchyma, 1024);
    GLOAD(x1, off, texture,    1024);

#define DO_CHUNK(L, P, X, imm) do {                                   \
    float v0 = s_lut[(L).x] * (X).x;                                  \
    float v1 = s_lut[(L).y] * (X).y;                                  \
    float v2 = s_lut[(L).z] * (X).z;                                  \
    float v3 = s_lut[(L).w] * (X).w;                                  \
    vfloat4 fv, mv;                                                   \
    fv.x = (P).x * ((v0 == 0.0f) ? 1.0f : v0);                        \
    fv.y = (P).y * ((v1 == 0.0f) ? 1.0f : v1);                        \
    fv.z = (P).z * ((v2 == 0.0f) ? 1.0f : v2);                        \
    fv.w = (P).w * ((v3 == 0.0f) ? 1.0f : v3);                        \
    mv.x = ((L).x != 0) ? 1.0f : 0.0f;                                \
    mv.y = ((L).y != 0) ? 1.0f : 0.0f;                                \
    mv.z = ((L).z != 0) ? 1.0f : 0.0f;                                \
    mv.w = ((L).w != 0) ? 1.0f : 0.0f;                                \
    GSTORE_NT(fv, off, out,  imm);                                    \
    GSTORE_NT(mv, off, outm, imm);                                    \
} while (0)

    // outstanding: 6 loads. wait(3) retires l0,p0,x0.
    WAITCNT_VM(3);
    DO_CHUNK(l0, p0, x0, 0);        // outstanding: 3 loads + 2 stores
    // wait(2) retires the 3 oldest = l1,p1,x1 (in-order).
    WAITCNT_VM(2);
    DO_CHUNK(l1, p1, x1, 1024);     // outstanding: 4 stores; drain at endpgm

#undef DO_CHUNK
}

extern "C" void kernel_launch(void* const* d_in, const int* in_sizes, int n_in,
                              void* d_out, int out_size, void* d_ws, size_t ws_size,
                              hipStream_t stream) {
    const int*   labels     = (const int*)d_in[0];
    const float* parenchyma = (const float*)d_in[1];
    const float* texture    = (const float*)d_in[2];
    const float* lut        = (const float*)d_in[3];
    float* out = (float*)d_out;

    // per block per stream: BLOCK*CHUNKS*16 B = 16 KB -> 64 MiB / 16 KB = 4096
    const int grid = (N_ELEMS * 4) / (BLOCK * CHUNKS * 16);   // 4096, no tail
    octvolsynth_r8<<<grid, BLOCK, 0, stream>>>(labels, parenchyma, texture, lut, out);
}

// Round 4
// 276.439 us; speedup vs baseline: 1.0186x; 1.0186x over previous
//
#include <hip/hip_runtime.h>

// OctVolSynth: element-wise over 256^3 volume.
//   scaling = lut[label]; v = scaling*texture; v = (v==0) ? 1 : v;
//   out0 = parenchyma * v;  out1 = (label != 0) ? 1.0f : 0.0f
//
// Record: R1/R5/R6/R7 = 98-99us across wildly different schedules; R7 proved
// intra-wave MLP (6 asm loads in flight, 8 waves/SIMD) changes nothing; R8
// proved nt stores don't move FETCH_SIZE (L3-thrash theory dead, nt -4%
// reverted). CU busy-time accounting shows ~80% stall with all pipes idle.
// Last untouched axis: block geometry -- all rounds ran 4096 short blocks
// (~16 generations/CU, occupancy 65%, pipeline drains to vmcnt=0 at every
// block boundary). R9: persistent exactly-resident grid (1024 blk x 512 thr
// = 32 waves/CU = 4 blk/CU), each block walks a contiguous 64KiB/stream
// region over 8 unrolled iterations with asm software pipelining, prefetch
// depth 2: vmcnt NEVER drains in the main loop (T3/T4 counted-vmcnt applied
// to streaming). Wait ladder [6,8,8,8,8,8,7,4] simulated against in-order
// vmcnt retire (stores counted). All vmem is asm (compiler must not emit
// scratch/vmem or counts break -- pressure kept ~70 VGPR, no spill);
// sched_barrier(0) after every wait (rule #18); tile slots A/B/C statically
// named (rule #20).

#define N_ELEMS (256 * 256 * 256)
#define LUT_SIZE 302
#define BLOCK 512
#define GRID 1024
#define TILE_BYTES 8192                 // per block per stream per iter (512*16)
#define BLK_BYTES (8 * TILE_BYTES)      // 64 KiB contiguous per stream per block

typedef float vfloat4 __attribute__((ext_vector_type(4)));
typedef int   vint4   __attribute__((ext_vector_type(4)));

#define GLOAD(dst, off, base)                                         \
  asm volatile("global_load_dwordx4 %0, %1, %2"                       \
               : "=&v"(dst) : "v"(off), "s"(base))

#define GSTORE(src, off, base)                                        \
  asm volatile("global_store_dwordx4 %0, %1, %2"                      \
               :: "v"(off), "v"(src), "s"(base) : "memory")

#define WAITSB(n)                                                     \
  do { asm volatile("s_waitcnt vmcnt(" #n ")" ::: "memory");          \
       __builtin_amdgcn_sched_barrier(0); } while (0)

__global__ __launch_bounds__(BLOCK, 8) void octvolsynth_r9(
    const int* __restrict__ labels,
    const float* __restrict__ parenchyma,
    const float* __restrict__ texture,
    const float* __restrict__ lut,
    float* __restrict__ out)
{
    __shared__ float s_lut[LUT_SIZE];
    for (int i = threadIdx.x; i < LUT_SIZE; i += BLOCK) s_lut[i] = lut[i];
    __syncthreads();   // drains vmcnt -> manual counting starts at 0

    const unsigned o0 = blockIdx.x * (unsigned)BLK_BYTES + threadIdx.x * 16u;
    const float* outm = out + N_ELEMS;   // mask plane base

    // tile register slots: tile t lives in slot t%3 (A,B,C)
    vint4   lA, lB, lC;
    vfloat4 pA, pB, pC, xA, xB, xC;

#define ISSUE(L, P, X, off) do {                                      \
    GLOAD(L, (off), labels);                                          \
    GLOAD(P, (off), parenchyma);                                      \
    GLOAD(X, (off), texture);                                         \
} while (0)

#define CONSUME(L, P, X, off) do {                                    \
    float v0 = s_lut[(L).x] * (X).x;                                  \
    float v1 = s_lut[(L).y] * (X).y;                                  \
    float v2 = s_lut[(L).z] * (X).z;                                  \
    float v3 = s_lut[(L).w] * (X).w;                                  \
    vfloat4 fv, mv;                                                   \
    fv.x = (P).x * ((v0 == 0.0f) ? 1.0f : v0);                        \
    fv.y = (P).y * ((v1 == 0.0f) ? 1.0f : v1);                        \
    fv.z = (P).z * ((v2 == 0.0f) ? 1.0f : v2);                        \
    fv.w = (P).w * ((v3 == 0.0f) ? 1.0f : v3);                        \
    mv.x = ((L).x != 0) ? 1.0f : 0.0f;                                \
    mv.y = ((L).y != 0) ? 1.0f : 0.0f;                                \
    mv.z = ((L).z != 0) ? 1.0f : 0.0f;                                \
    mv.w = ((L).w != 0) ? 1.0f : 0.0f;                                \
    GSTORE(fv, (off), out);                                           \
    GSTORE(mv, (off), outm);                                          \
} while (0)

    // ---- prologue: tiles 0,1 in flight (6 loads outstanding) ----
    ISSUE(lA, pA, xA, o0 + 0 * TILE_BYTES);   // T0 -> slot A
    ISSUE(lB, pB, xB, o0 + 1 * TILE_BYTES);   // T1 -> slot B

    // ---- steady pipeline: issue T(t+2), wait ladder, consume T(t) ----
    // outstanding sets verified by oldest-first simulation (stores counted):
    // i0: +T2 =9  w(6) -> [T1,T2]           ; i1: +T3 =11 w(8) -> [T2,S0,T3]
    // i2..i5:    +T(t+2) =13 w(8) -> [T(t+1),S(t-1),T(t+2)]
    // i6: no issue, w(7) retires T6         ; i7: w(4) retires T7
    ISSUE(lC, pC, xC, o0 + 2 * TILE_BYTES);                   // i0: T2 -> C
    WAITSB(6);  CONSUME(lA, pA, xA, o0 + 0 * TILE_BYTES);     // T0

    ISSUE(lA, pA, xA, o0 + 3 * TILE_BYTES);                   // i1: T3 -> A
    WAITSB(8);  CONSUME(lB, pB, xB, o0 + 1 * TILE_BYTES);     // T1

    ISSUE(lB, pB, xB, o0 + 4 * TILE_BYTES);                   // i2: T4 -> B
    WAITSB(8);  CONSUME(lC, pC, xC, o0 + 2 * TILE_BYTES);     // T2

    ISSUE(lC, pC, xC, o0 + 5 * TILE_BYTES);                   // i3: T5 -> C
    WAITSB(8);  CONSUME(lA, pA, xA, o0 + 3 * TILE_BYTES);     // T3

    ISSUE(lA, pA, xA, o0 + 6 * TILE_BYTES);                   // i4: T6 -> A
    WAITSB(8);  CONSUME(lB, pB, xB, o0 + 4 * TILE_BYTES);     // T4

    ISSUE(lB, pB, xB, o0 + 7 * TILE_BYTES);                   // i5: T7 -> B
    WAITSB(8);  CONSUME(lC, pC, xC, o0 + 5 * TILE_BYTES);     // T5

    WAITSB(7);  CONSUME(lA, pA, xA, o0 + 6 * TILE_BYTES);     // i6: T6
    WAITSB(4);  CONSUME(lB, pB, xB, o0 + 7 * TILE_BYTES);     // i7: T7

#undef ISSUE
#undef CONSUME
}

extern "C" void kernel_launch(void* const* d_in, const int* in_sizes, int n_in,
                              void* d_out, int out_size, void* d_ws, size_t ws_size,
                              hipStream_t stream) {
    const int*   labels     = (const int*)d_in[0];
    const float* parenchyma = (const float*)d_in[1];
    const float* texture    = (const float*)d_in[2];
    const float* lut        = (const float*)d_in[3];
    float* out = (float*)d_out;

    // 1024 blocks x 512 thr x 8 iters x 4 float4-elems... :
    // 1024 * 64KiB per stream = 64 MiB = full plane, no tail.
    octvolsynth_r9<<<GRID, BLOCK, 0, stream>>>(labels, parenchyma, texture, lut, out);
}

// Round 5
// 271.018 us; speedup vs baseline: 1.0389x; 1.0200x over previous
//
#include <hip/hip_runtime.h>

// OctVolSynth: element-wise over 256^3 volume.
//   scaling = lut[label]; v = scaling*texture; v = (v==0) ? 1 : v;
//   out0 = parenchyma * v;  out1 = (label != 0) ? 1.0f : 0.0f
//
// Session record: R1/R5/R6/R7 (forced 6-deep asm MLP) /R8 (nt stores) /R9
// (persistent 32-wave/CU depth-2 counted-vmcnt pipeline) ALL land at 99us
// +/-4%, FETCH bit-identical ~96MiB, WRITE exactly 128MiB. Every CU-side
// axis falsified: MLP null, cache policy null, geometry null, pipeline-drain
// null. Combined device traffic pinned at ~3.2 TB/s (51% of the m13 copy
// anchor) with all CU pipes idle.
//
// R10 probes the one untested corner: the BabelStream archetype. All prior
// variants used dwordx4 (1KB wave bursts x 5 lockstep streams, <=67%
// occupancy). BabelStream-class streaming on this HW family reaches 85-90%
// of peak with the opposite shape: scalar 4B/lane (256B wave bursts ->
// finer channel interleave of the 5 streams), 1024-thread blocks, 1 elem/
// thread, ~12 VGPR, ~100% occupancy, no asm, compiler-scheduled. If this is
// ALSO ~99us, the invariance is conclusively system-level and the next round
// declares the structural ceiling.

#define N_ELEMS (256 * 256 * 256)
#define LUT_SIZE 302
#define BLOCK 1024

__global__ __launch_bounds__(BLOCK) void octvolsynth_r10(
    const int* __restrict__ labels,
    const float* __restrict__ parenchyma,
    const float* __restrict__ texture,
    const float* __restrict__ lut,
    float* __restrict__ out)
{
    __shared__ float s_lut[LUT_SIZE];
    for (int i = threadIdx.x; i < LUT_SIZE; i += BLOCK) s_lut[i] = lut[i];
    __syncthreads();

    const int i = blockIdx.x * BLOCK + threadIdx.x;   // one element per thread

    const int   l = labels[i];
    const float p = parenchyma[i];
    const float x = texture[i];

    float v = s_lut[l] * x;
    v = (v == 0.0f) ? 1.0f : v;

    out[i]           = p * v;
    out[N_ELEMS + i] = (l != 0) ? 1.0f : 0.0f;
}

extern "C" void kernel_launch(void* const* d_in, const int* in_sizes, int n_in,
                              void* d_out, int out_size, void* d_ws, size_t ws_size,
                              hipStream_t stream) {
    const int*   labels     = (const int*)d_in[0];
    const float* parenchyma = (const float*)d_in[1];
    const float* texture    = (const float*)d_in[2];
    const float* lut        = (const float*)d_in[3];
    float* out = (float*)d_out;

    const int grid = N_ELEMS / BLOCK;   // 16384 blocks, no tail
    octvolsynth_r10<<<grid, BLOCK, 0, stream>>>(labels, parenchyma, texture, lut, out);
}